// Round 2
// baseline (734135.010 us; speedup 1.0000x reference)
//
#include <hip/hip_runtime.h>
#include <hip/hip_bf16.h>
#include <math.h>

typedef __hip_bfloat16 bf16;

#define B_    32
#define L_    12
#define C_    768
#define H_    12
#define DH_   64
#define M_    64
#define NP_   197
#define HID_  3072
#define NCLS_ 1000
#define NTOK   (B_*NP_)    /* 6304 */
#define NPATCH (B_*196)    /* 6272 */

typedef unsigned long long u64;

// dtype-agnostic input load from BASE pointer + global element index.
// isb=1 -> underlying bf16, isb=0 -> fp32.
__device__ __forceinline__ float ldin(const void* p, int isb, u64 i){
  return isb ? __bfloat162float(((const bf16*)p)[i]) : ((const float*)p)[i];
}

// ---------------- detect input dtype from ln1_w (== ones) ----------------
__global__ void k_detect(const void* ln1w, int* flag){
  if (threadIdx.x==0 && blockIdx.x==0)
    *flag = (((const unsigned*)ln1w)[0] == 0x3F800000u) ? 0 : 1;
}

// ---------------- im2col for 16x16/s16 patch conv ----------------
__global__ void k_im2col(const void* __restrict__ x, float* __restrict__ P,
                         const int* __restrict__ flag){
  int isb = *flag;
  int idx = blockIdx.x*256 + threadIdx.x;
  if (idx >= NPATCH*768) return;
  int row = idx / 768, col = idx - row*768;
  int b = row / 196, p = row - b*196;
  int py = p / 14, px = p - py*14;
  int i = col >> 8, r = col & 255, ky = r >> 4, kx = r & 15;
  P[idx] = ldin(x, isb, ((u64)(b*3+i)*224 + py*16+ky)*224 + px*16 + kx);
}

// ---------------- assemble tokens: cls + patches + pos ----------------
__global__ void k_assemble(const float* __restrict__ PG, const void* __restrict__ patch_b,
                           const void* __restrict__ cls, const void* __restrict__ pos,
                           float* __restrict__ T, const int* __restrict__ flag){
  int isb = *flag;
  int idx = blockIdx.x*256 + threadIdx.x;
  if (idx >= NTOK*C_) return;
  int c = idx % C_; int t = idx / C_; int n = t % NP_; int b = t / NP_;
  float v;
  if (n == 0) v = ldin(cls, isb, c) + ldin(pos, isb, c);
  else v = PG[(u64)(b*196 + n-1)*C_ + c] + ldin(patch_b, isb, c)
         + ldin(pos, isb, (u64)n*C_ + c);
  T[idx] = v;
}

// ---------------- LayerNorm (one 256-thread block per row of 768) ----------------
__global__ void k_ln(const float* __restrict__ X, const void* __restrict__ w,
                     const void* __restrict__ bb, float* __restrict__ Y, int rowStride,
                     const int* __restrict__ flag, u64 wOff){
  int isb = *flag;
  int r = blockIdx.x;
  const float* xr = X + (u64)r*rowStride*C_;
  float* yr = Y + (u64)r*C_;
  int tid = threadIdx.x;
  float v[3]; float s = 0.f;
  #pragma unroll
  for (int j=0;j<3;j++){ v[j] = xr[tid + j*256]; s += v[j]; }
  __shared__ float red[256];
  red[tid] = s; __syncthreads();
  for (int off=128; off>0; off>>=1){ if (tid<off) red[tid]+=red[tid+off]; __syncthreads(); }
  float mu = red[0] * (1.0f/768.0f);
  __syncthreads();
  float s2 = 0.f;
  #pragma unroll
  for (int j=0;j<3;j++){ float d = v[j]-mu; s2 += d*d; }
  red[tid] = s2; __syncthreads();
  for (int off=128; off>0; off>>=1){ if (tid<off) red[tid]+=red[tid+off]; __syncthreads(); }
  float rs = rsqrtf(red[0]*(1.0f/768.0f) + 1e-6f);
  #pragma unroll
  for (int j=0;j<3;j++){ int c = tid + j*256;
    yr[c] = (v[j]-mu)*rs*ldin(w,isb,wOff+c) + ldin(bb,isb,wOff+c); }
}

// ---------------- generic tiled GEMM: C = A(fp32, RowsxK) @ W(NxK)^T ----------------
#define GBM 128
#define GBN 128
#define GBK 16
enum {EPI_STORE=0, EPI_GELU=1, EPI_RES=2, EPI_OUT=3};

__global__ __launch_bounds__(256) void k_gemm(const float* __restrict__ A,
        const void* __restrict__ W, const void* __restrict__ bias,
        float* __restrict__ D, void* __restrict__ Oany, const int* __restrict__ flag,
        int Rows, int N, int K, int epi, u64 wOff, u64 bOff){
  int isb = *flag;
  __shared__ float As[GBM][GBK+1];
  __shared__ float Bs[GBN][GBK+1];
  int tid = threadIdx.x;
  int tx = tid & 15, ty = tid >> 4;
  int rb = blockIdx.y * GBM, cb = blockIdx.x * GBN;
  float acc[8][8] = {};
  for (int k0 = 0; k0 < K; k0 += GBK){
    for (int e = tid; e < GBM*GBK; e += 256){
      int r = e >> 4, kk = e & 15;
      int row = rb + r;
      As[r][kk] = (row < Rows) ? A[(u64)row*K + k0 + kk] : 0.f;
    }
    for (int e = tid; e < GBN*GBK; e += 256){
      int n = e >> 4, kk = e & 15;
      int col = cb + n;
      Bs[n][kk] = (col < N) ? ldin(W, isb, wOff + (u64)col*K + k0 + kk) : 0.f;
    }
    __syncthreads();
    #pragma unroll
    for (int kk = 0; kk < GBK; kk++){
      float a[8], bv[8];
      #pragma unroll
      for (int i=0;i<8;i++) a[i] = As[ty*8+i][kk];
      #pragma unroll
      for (int j=0;j<8;j++) bv[j] = Bs[tx*8+j][kk];
      #pragma unroll
      for (int i=0;i<8;i++)
        #pragma unroll
        for (int j=0;j<8;j++) acc[i][j] += a[i]*bv[j];
    }
    __syncthreads();
  }
  for (int i=0;i<8;i++){
    int row = rb + ty*8 + i; if (row >= Rows) continue;
    for (int j=0;j<8;j++){
      int col = cb + tx*8 + j; if (col >= N) continue;
      float v = acc[i][j] + (bias ? ldin(bias, isb, bOff + col) : 0.f);
      if (epi == EPI_STORE)      D[(u64)row*N+col] = v;
      else if (epi == EPI_GELU)  D[(u64)row*N+col] = 0.5f*v*(1.0f + erff(v*0.70710678118654752f));
      else if (epi == EPI_RES)   D[(u64)row*N+col] += v;
      else {
        if (isb) ((bf16*)Oany)[(u64)row*N+col] = __float2bfloat16(v);
        else     ((float*)Oany)[(u64)row*N+col] = v;
      }
    }
  }
}

// ---------------- Performer phi(k): store dd-diag raw + per-row max ----------------
__global__ __launch_bounds__(64) void k_phi_k(const float* __restrict__ QKV,
        const void* __restrict__ worf, float* __restrict__ KP, float* __restrict__ rowmax,
        const int* __restrict__ flag, u64 wOff){
  int isb = *flag;
  int rid = blockIdx.x;              // (b*197+l)*12 + h
  int h = rid % 12; int bl = rid / 12;
  int m = threadIdx.x;
  __shared__ float kvec[64];
  float kd = QKV[(u64)bl*2304 + 768 + h*64 + m];
  kvec[m] = kd;
  float s = kd;
  #pragma unroll
  for (int off=32; off; off>>=1) s += __shfl_xor(s, off);
  float diag = s * 0.0625f;          // sum/2 * dn^2, dn^2 = 1/8
  __syncthreads();
  float dd = 0.f;
  #pragma unroll 8
  for (int d=0; d<64; d++) dd += kvec[d]*ldin(worf, isb, wOff + (u64)m*64 + d);
  float mx = dd;
  #pragma unroll
  for (int off=32; off; off>>=1) mx = fmaxf(mx, __shfl_xor(mx, off));
  KP[(u64)rid*64 + m] = dd - diag;
  if (m==0) rowmax[rid] = mx;
}

// ---------------- Performer phi(q) ----------------
__global__ __launch_bounds__(64) void k_phi_q(const float* __restrict__ QKV,
        const void* __restrict__ worf, float* __restrict__ QP,
        const int* __restrict__ flag, u64 wOff){
  int isb = *flag;
  int rid = blockIdx.x;
  int h = rid % 12; int bl = rid / 12;
  int m = threadIdx.x;
  __shared__ float qvec[64];
  float qd = QKV[(u64)bl*2304 + h*64 + m];
  qvec[m] = qd;
  float s = qd;
  #pragma unroll
  for (int off=32; off; off>>=1) s += __shfl_xor(s, off);
  float diag = s * 0.0625f;
  __syncthreads();
  float dd = 0.f;
  #pragma unroll 8
  for (int d=0; d<64; d++) dd += qvec[d]*ldin(worf, isb, wOff + (u64)m*64 + d);
  float mx = dd;
  #pragma unroll
  for (int off=32; off; off>>=1) mx = fmaxf(mx, __shfl_xor(mx, off));
  QP[(u64)rid*64 + m] = 0.35355339059327f*(expf(dd - diag - mx) + 1e-6f);
}

// ---------------- global max over rowmax ----------------
__global__ void k_maxreduce(const float* __restrict__ rowmax, float* __restrict__ S, int n){
  __shared__ float red[256];
  float m = -1e30f;
  for (int i=threadIdx.x; i<n; i+=256) m = fmaxf(m, rowmax[i]);
  red[threadIdx.x] = m; __syncthreads();
  for (int off=128; off; off>>=1){ if (threadIdx.x<off) red[threadIdx.x]=fmaxf(red[threadIdx.x],red[threadIdx.x+off]); __syncthreads(); }
  if (threadIdx.x==0) *S = red[0];
}

// ---------------- exp for keys with global stab ----------------
__global__ void k_expk(float* __restrict__ KP, const float* __restrict__ S, int n){
  int i = blockIdx.x*256 + threadIdx.x;
  if (i < n) KP[i] = 0.35355339059327f*(expf(KP[i] - *S) + 1e-6f);
}

// ---------------- kv[b,h,m,d] = sum_l kp * v ; ks[b,h,m] = sum_l kp ----------------
__global__ __launch_bounds__(256) void k_kv(const float* __restrict__ KP,
        const float* __restrict__ QKV, float* __restrict__ KV, float* __restrict__ KS){
  int bh = blockIdx.x; int b = bh/12, h = bh - b*12;
  int t = threadIdx.x;
  int d = t & 63, mg = t >> 6;
  __shared__ float kps[64], vs[64];
  float acc[16] = {};
  float ksacc = 0.f;
  for (int l=0; l<NP_; l++){
    u64 bl = (u64)(b*NP_ + l);
    if (t < 64) kps[t] = KP[(bl*12 + h)*64 + t];
    else if (t < 128) vs[t-64] = QKV[bl*2304 + 1536 + h*64 + (t-64)];
    __syncthreads();
    float vd = vs[d];
    #pragma unroll
    for (int j=0;j<16;j++) acc[j] += kps[mg*16+j]*vd;
    if (t < 64) ksacc += kps[t];
    __syncthreads();
  }
  float* kvb = KV + (u64)bh*64*64;
  #pragma unroll
  for (int j=0;j<16;j++) kvb[(u64)(mg*16+j)*64 + d] = acc[j];
  if (t < 64) KS[(u64)bh*64 + t] = ksacc;
}

// ---------------- num/D -> attention head output ----------------
__global__ __launch_bounds__(64) void k_numd(const float* __restrict__ QP,
        const float* __restrict__ KV, const float* __restrict__ KS, float* __restrict__ OUT){
  int rid = blockIdx.x;             // (b*197+l)*12 + h
  int h = rid % 12; int bl = rid / 12; int b = bl / NP_;
  int t = threadIdx.x;
  __shared__ float qs[64];
  float q = QP[(u64)rid*64 + t];
  qs[t] = q;
  int bh = b*12 + h;
  float dp = q * KS[(u64)bh*64 + t];
  #pragma unroll
  for (int off=32; off; off>>=1) dp += __shfl_xor(dp, off);
  __syncthreads();
  const float* kvb = KV + (u64)bh*4096;
  float acc = 0.f;
  #pragma unroll 8
  for (int m=0;m<64;m++) acc += qs[m]*kvb[(u64)m*64 + t];
  OUT[(u64)bl*768 + h*64 + t] = acc / dp;
}

extern "C" void kernel_launch(void* const* d_in, const int* in_sizes, int n_in,
                              void* d_out, int out_size, void* d_ws, size_t ws_size,
                              hipStream_t stream) {
  const void* x        = d_in[0];
  const void* patch_w  = d_in[1];
  const void* patch_b  = d_in[2];
  const void* cls_tok  = d_in[3];
  const void* pos_emb  = d_in[4];
  const void* ln1_w    = d_in[5];
  const void* ln1_b    = d_in[6];
  const void* qkv_w    = d_in[7];
  const void* qkv_b    = d_in[8];
  const void* w_orf    = d_in[9];
  const void* proj_w   = d_in[10];
  const void* proj_b   = d_in[11];
  const void* ln2_w    = d_in[12];
  const void* ln2_b    = d_in[13];
  const void* fc1_w    = d_in[14];
  const void* fc1_b    = d_in[15];
  const void* fc2_w    = d_in[16];
  const void* fc2_b    = d_in[17];
  const void* lnf_w    = d_in[18];
  const void* lnf_b    = d_in[19];
  const void* head_w   = d_in[20];
  const void* head_b   = d_in[21];

  float* ws = (float*)d_ws;
  const u64 SZ_TOKC = (u64)NTOK*C_;       // 4,841,472
  const u64 SZ_BIG  = (u64)NTOK*HID_;     // 19,365,888
  const u64 SZ_PHI  = (u64)NTOK*H_*M_;    // 4,841,472
  const u64 SZ_KV   = (u64)B_*H_*M_*DH_;  // 1,572,864
  const u64 SZ_KS   = (u64)B_*H_*M_;      // 24,576
  const u64 SZ_RMX  = (u64)NTOK*H_;       // 75,648

  float* T   = ws;
  float* LNB = T   + SZ_TOKC;
  float* BIG = LNB + SZ_TOKC;
  float* QP  = BIG + SZ_BIG;
  float* KP  = QP  + SZ_PHI;
  float* KV  = KP  + SZ_PHI;
  float* KS  = KV  + SZ_KV;
  float* RMX = KS  + SZ_KS;
  float* SS  = RMX + SZ_RMX;
  int*   FLG = (int*)(SS + 16);
  float* CLS = SS  + 32;

  k_detect<<<1, 64, 0, stream>>>(ln1_w, FLG);

  // patch embed: im2col -> GEMM -> assemble tokens
  k_im2col<<<(NPATCH*768+255)/256, 256, 0, stream>>>(x, BIG, FLG);
  k_gemm<<<dim3(6,49), 256, 0, stream>>>(BIG, patch_w, nullptr, LNB, nullptr, FLG,
                                         NPATCH, 768, 768, EPI_STORE, 0, 0);
  k_assemble<<<(NTOK*C_+255)/256, 256, 0, stream>>>(LNB, patch_b, cls_tok, pos_emb, T, FLG);

  const int NRID = NTOK*H_;   // 75648
  for (int i = 0; i < L_; i++){
    u64 oQW = (u64)i*2304*C_, oQB = (u64)i*2304;
    u64 oPW = (u64)i*C_*C_,   oPB = (u64)i*C_;
    u64 o1W = (u64)i*HID_*C_, o1B = (u64)i*HID_;
    u64 o2W = (u64)i*C_*HID_, o2B = (u64)i*C_;
    u64 oL  = (u64)i*C_;
    u64 oRF = (u64)i*M_*DH_;
    // --- attention ---
    k_ln<<<NTOK, 256, 0, stream>>>(T, ln1_w, ln1_b, LNB, 1, FLG, oL);
    k_gemm<<<dim3(18,50), 256, 0, stream>>>(LNB, qkv_w, qkv_b, BIG, nullptr, FLG,
                                            NTOK, 2304, 768, EPI_STORE, oQW, oQB);
    k_phi_k<<<NRID, 64, 0, stream>>>(BIG, w_orf, KP, RMX, FLG, oRF);
    k_maxreduce<<<1, 256, 0, stream>>>(RMX, SS, NRID);
    k_expk<<<(int)((SZ_PHI+255)/256), 256, 0, stream>>>(KP, SS, (int)SZ_PHI);
    k_phi_q<<<NRID, 64, 0, stream>>>(BIG, w_orf, QP, FLG, oRF);
    k_kv<<<B_*H_, 256, 0, stream>>>(KP, BIG, KV, KS);
    k_numd<<<NRID, 64, 0, stream>>>(QP, KV, KS, LNB);
    k_gemm<<<dim3(6,50), 256, 0, stream>>>(LNB, proj_w, proj_b, T, nullptr, FLG,
                                           NTOK, 768, 768, EPI_RES, oPW, oPB);
    // --- MLP ---
    k_ln<<<NTOK, 256, 0, stream>>>(T, ln2_w, ln2_b, LNB, 1, FLG, oL);
    k_gemm<<<dim3(24,50), 256, 0, stream>>>(LNB, fc1_w, fc1_b, BIG, nullptr, FLG,
                                            NTOK, 3072, 768, EPI_GELU, o1W, o1B);
    k_gemm<<<dim3(6,50), 256, 0, stream>>>(BIG, fc2_w, fc2_b, T, nullptr, FLG,
                                           NTOK, 768, 3072, EPI_RES, o2W, o2B);
  }

  // final LN on cls rows only + head
  k_ln<<<B_, 256, 0, stream>>>(T, lnf_w, lnf_b, CLS, NP_, FLG, 0);
  k_gemm<<<dim3(8,1), 256, 0, stream>>>(CLS, head_w, head_b, nullptr, d_out, FLG,
                                        B_, NCLS_, 768, EPI_OUT, 0, 0);
}